// Round 18
// baseline (3466.647 us; speedup 1.0000x reference)
//
#include <hip/hip_runtime.h>

#define NR 512
#define NI 128
#define B 32
#define T 1000
#define G 16
// Locked numeric model (verified PASS rounds 13-17):
//  - input GEMM: per element single ascending-i FMA chain.
//  - z @ w_rec_masked: two 256-wide ascending-k chains (OpenBLAS K-panel
//    rebalancing: [0,256)+[256,512)), joined by one rounded add.
//    Binary z => only active rows; masked diag and zero-row pads are exact +0.
//  - elementwise: separate rounded f32 ops ((f32(decay)*v) + i_t) - z.
//  - pred: EMA over (b_out + spikes@w_out), f64, post-hoc in k_pred (loose tol).
// This round: T4 counted-vmcnt pipeline — asm loads + explicit vmcnt(48/32/16/0),
// depth 4x16; compiler can no longer serialize the prefetch.

__device__ __forceinline__ float mul_nofma(float a, float b) {
    float r = a * b;
    asm volatile("" : "+v"(r));
    return r;
}

// LDS-only barrier: leaves global loads/stores in flight.
__device__ __forceinline__ void bar_lds() {
    asm volatile("s_waitcnt lgkmcnt(0)\n\ts_barrier" ::: "memory");
}

// Raw global load: no compiler waitcnt tracking, stays put (volatile).
__device__ __forceinline__ float gload(const float* rp, int voffb) {
    float r;
    asm volatile("global_load_dword %0, %1, %2"
                 : "=v"(r) : "v"(voffb), "s"(rp));
    return r;
}

#define PINS(bf) "+v"(bf[0]),"+v"(bf[1]),"+v"(bf[2]),"+v"(bf[3]),"+v"(bf[4]),\
                 "+v"(bf[5]),"+v"(bf[6]),"+v"(bf[7]),"+v"(bf[8]),"+v"(bf[9]),\
                 "+v"(bf[10]),"+v"(bf[11]),"+v"(bf[12]),"+v"(bf[13]),"+v"(bf[14]),"+v"(bf[15])

// Wait until this group's 16 loads are back: with D=4 groups in flight the
// target count is (remaining groups)*16, capped at 48. rem is block-uniform.
__device__ __forceinline__ void waitg(float (&bf)[G], int rem) {
    if (rem >= 3)      asm volatile("s_waitcnt vmcnt(48)" : PINS(bf));
    else if (rem == 2) asm volatile("s_waitcnt vmcnt(32)" : PINS(bf));
    else if (rem == 1) asm volatile("s_waitcnt vmcnt(16)" : PINS(bf));
    else               asm volatile("s_waitcnt vmcnt(0)"  : PINS(bf));
}

// ---------------- Kernel 0: masked w_rec copy + zero row into d_ws
__global__ __launch_bounds__(512) void k_prep(const float* __restrict__ w_rec,
                                              float* __restrict__ w_ws) {
    const int r = blockIdx.x, u = threadIdx.x;
    float val = 0.f;
    if (r < NR && r != u) val = w_rec[r * NR + u];
    w_ws[r * NR + u] = val;
}

// ---------------- Kernel 1: i_in = inputs @ w_in -> voltages region of d_out
template <int ROWS>
__global__ __launch_bounds__(512) void k_in_gemm(const float* __restrict__ inputs,
                                                 const float* __restrict__ w_in,
                                                 float* __restrict__ i_in) {
    const int u = threadIdx.x;
    const int r0 = blockIdx.x * ROWS;
    float acc[ROWS];
#pragma unroll
    for (int r = 0; r < ROWS; ++r) acc[r] = 0.f;
    const float* __restrict__ inp = inputs + (long)r0 * NI;
#pragma unroll 4
    for (int i = 0; i < NI; ++i) {
        float w = w_in[i * NR + u];
#pragma unroll
        for (int r = 0; r < ROWS; ++r)
            acc[r] = __builtin_fmaf(inp[r * NI + i], w, acc[r]);   // ascending i, FMA
    }
#pragma unroll
    for (int r = 0; r < ROWS; ++r)
        i_in[(long)(r0 + r) * NR + u] = acc[r];
}

// issue one 16-wide group of scalar loads (rows from list, own column u)
__device__ __forceinline__ void issueg(float (&bf)[G], const int* __restrict__ lp,
                                       const float* __restrict__ w_ws, int voffb) {
    int4 ja = *(const int4*)(lp + 0);
    int4 jb = *(const int4*)(lp + 4);
    int4 jc = *(const int4*)(lp + 8);
    int4 jd = *(const int4*)(lp + 12);
    bf[0]  = gload(w_ws + __builtin_amdgcn_readfirstlane(ja.x) * NR, voffb);
    bf[1]  = gload(w_ws + __builtin_amdgcn_readfirstlane(ja.y) * NR, voffb);
    bf[2]  = gload(w_ws + __builtin_amdgcn_readfirstlane(ja.z) * NR, voffb);
    bf[3]  = gload(w_ws + __builtin_amdgcn_readfirstlane(ja.w) * NR, voffb);
    bf[4]  = gload(w_ws + __builtin_amdgcn_readfirstlane(jb.x) * NR, voffb);
    bf[5]  = gload(w_ws + __builtin_amdgcn_readfirstlane(jb.y) * NR, voffb);
    bf[6]  = gload(w_ws + __builtin_amdgcn_readfirstlane(jb.z) * NR, voffb);
    bf[7]  = gload(w_ws + __builtin_amdgcn_readfirstlane(jb.w) * NR, voffb);
    bf[8]  = gload(w_ws + __builtin_amdgcn_readfirstlane(jc.x) * NR, voffb);
    bf[9]  = gload(w_ws + __builtin_amdgcn_readfirstlane(jc.y) * NR, voffb);
    bf[10] = gload(w_ws + __builtin_amdgcn_readfirstlane(jc.z) * NR, voffb);
    bf[11] = gload(w_ws + __builtin_amdgcn_readfirstlane(jc.w) * NR, voffb);
    bf[12] = gload(w_ws + __builtin_amdgcn_readfirstlane(jd.x) * NR, voffb);
    bf[13] = gload(w_ws + __builtin_amdgcn_readfirstlane(jd.y) * NR, voffb);
    bf[14] = gload(w_ws + __builtin_amdgcn_readfirstlane(jd.z) * NR, voffb);
    bf[15] = gload(w_ws + __builtin_amdgcn_readfirstlane(jd.w) * NR, voffb);
}

__device__ __forceinline__ void sumg(const float (&bf)[G], int g, int nlo,
                                     float& s1, float& s2) {
    float& s = (g < nlo) ? s1 : s2;
#pragma unroll
    for (int q = 0; q < G; ++q) s = __fadd_rn(s, bf[q]);
}

#define LPTR(gg) (((gg) < nlo) ? (listA + (gg) * G) : (listB + ((gg) - nlo) * G))

// ---------------- Kernel 2: per-batch LIF scan, counted-vmcnt pipelined gather.
__global__ __launch_bounds__(512) void k_scan(const float* __restrict__ w_ws,
                                              float* __restrict__ out) {
    const int b = blockIdx.x;
    const int u = threadIdx.x;
    const int wav = u >> 6, lane = u & 63;
    const int voffb = u * 4;

    float* __restrict__ volt_b = out + (long)b * (T * NR);                 // also i_in (in-place)
    float* __restrict__ spk_b  = out + (long)B * T * NR + (long)b * (T * NR);

    __shared__ __align__(16) int listA[256];
    __shared__ __align__(16) int listB[256];
    __shared__ int wcnt[8];

    float v = 0.f, z = 0.f;
    const float decay = 0.951229424500714f;   // f32 rounding of the python scalar

    for (int t = 0; t < T; ++t) {
        float ii = volt_b[t * NR + u];         // prefetch; oldest vmcnt entry

        unsigned long long m = __ballot(z > 0.5f);
        if (lane == 0) wcnt[wav] = __popcll(m);
        bar_lds();                             // A: wcnt ready

        const int c0 = wcnt[0], c1 = wcnt[1], c2 = wcnt[2], c3 = wcnt[3];
        const int c4 = wcnt[4], c5 = wcnt[5], c6 = wcnt[6], c7 = wcnt[7];
        const int cnt_lo = c0 + c1 + c2 + c3;
        const int cnt_hi = c4 + c5 + c6 + c7;

        // scatter actives into per-panel lists (ascending u within each panel)
        if (z > 0.5f) {
            int below = __popcll(m & ((1ull << lane) - 1ull));
            if (wav < 4) {
                int pos = (wav > 0 ? c0 : 0) + (wav > 1 ? c1 : 0) + (wav > 2 ? c2 : 0) + below;
                listA[pos] = u;
            } else {
                int pos = (wav > 4 ? c4 : 0) + (wav > 5 ? c5 : 0) + (wav > 6 ? c6 : 0) + below;
                listB[pos] = u;
            }
        }
        // refresh stale slots -> zero row (disjoint from scatter targets)
        if (u < 256) { if (u >= cnt_lo) listA[u] = NR; }
        else         { int x = u - 256; if (x >= cnt_hi) listB[x] = NR; }
        bar_lds();                             // B: lists ready

        // ---- two-panel chain, counted-vmcnt pipeline, 4x16 in flight
        const int nlo = (cnt_lo + G - 1) >> 4;
        const int ng  = nlo + ((cnt_hi + G - 1) >> 4);
        float s1 = 0.f, s2 = 0.f;
        if (ng > 0) {
            float b0[G], b1[G], b2[G], b3[G];
            issueg(b0, LPTR(0), w_ws, voffb);
            if (ng > 1) issueg(b1, LPTR(1), w_ws, voffb);
            if (ng > 2) issueg(b2, LPTR(2), w_ws, voffb);
            if (ng > 3) issueg(b3, LPTR(3), w_ws, voffb);
            int g = 0;
            while (true) {
                waitg(b0, ng - 1 - g); sumg(b0, g, nlo, s1, s2);
                if (g + 4 < ng) issueg(b0, LPTR(g + 4), w_ws, voffb);
                if (++g == ng) break;
                waitg(b1, ng - 1 - g); sumg(b1, g, nlo, s1, s2);
                if (g + 4 < ng) issueg(b1, LPTR(g + 4), w_ws, voffb);
                if (++g == ng) break;
                waitg(b2, ng - 1 - g); sumg(b2, g, nlo, s1, s2);
                if (g + 4 < ng) issueg(b2, LPTR(g + 4), w_ws, voffb);
                if (++g == ng) break;
                waitg(b3, ng - 1 - g); sumg(b3, g, nlo, s1, s2);
                if (g + 4 < ng) issueg(b3, LPTR(g + 4), w_ws, voffb);
                if (++g == ng) break;
            }
        }
        float rec = __fadd_rn(s1, s2);         // panel join (one rounded add)

        // ---- LIF update (reference op order, no contraction)
        float it = __fadd_rn(ii, rec);
        float m1 = mul_nofma(decay, v);
        float t2 = __fadd_rn(m1, it);
        float vn = __fsub_rn(t2, z);
        float zn = (vn > 1.0f) ? 1.0f : 0.0f;
        volt_b[t * NR + u] = vn;
        spk_b[t * NR + u]  = zn;
        v = vn; z = zn;
    }
}

// ---------------- Kernel 3: pred = EMA(b_out + spikes @ w_out), post-hoc.
__global__ __launch_bounds__(512) void k_pred(const float* __restrict__ w_out,
                                              const float* __restrict__ b_out,
                                              float* __restrict__ out) {
    const int b = blockIdx.x;
    const int tid = threadIdx.x;
    const int wav = tid >> 6, lane = tid & 63;
    const float* __restrict__ spk_b = out + (long)B * T * NR + (long)b * (T * NR);
    float* __restrict__ pred = out + 2L * B * T * NR + (long)b * T;

    __shared__ double projs[T];   // 8 KB

    double wo[8];
#pragma unroll
    for (int q = 0; q < 8; ++q) wo[q] = (double)w_out[lane + q * 64];

    for (int t = wav; t < T; t += 8) {
        double p = 0.0;
#pragma unroll
        for (int q = 0; q < 8; ++q)
            p += (double)spk_b[t * NR + lane + q * 64] * wo[q];
#pragma unroll
        for (int o = 32; o > 0; o >>= 1) p += __shfl_xor(p, o, 64);
        if (lane == 0) projs[t] = p;
    }
    __syncthreads();
    if (tid == 0) {
        const double bo = (double)b_out[0];
        double ema = 0.0;
        for (int t = 0; t < T; ++t) {
            ema = 0.8 * ema + 0.2 * (bo + projs[t]);
            pred[t] = (float)ema;
        }
    }
}

// ---------------- Fallback: verified round-13 scan (no d_ws needed)
__global__ __launch_bounds__(512) void k_scan_ref(const float* __restrict__ w_rec,
                                                  const float* __restrict__ w_out,
                                                  const float* __restrict__ b_out,
                                                  float* __restrict__ out) {
    const int b = blockIdx.x;
    const int u = threadIdx.x;
    const int wav = u >> 6, lane = u & 63;
    const int KC = 256;

    float* __restrict__ volt_b = out + (long)b * (T * NR);
    float* __restrict__ spk_b  = out + (long)B * T * NR + (long)b * (T * NR);
    float* __restrict__ pred   = out + 2L * B * T * NR;

    __shared__ __align__(16) int list[NR];
    __shared__ int wcnt[8];
    __shared__ double projp[8];

    float v = 0.f, z = 0.f;
    const float decay = 0.951229424500714f;
    const double wo = (double)w_out[u];
    const double bo = (double)b_out[0];
    double ema = 0.0;

    for (int t = 0; t < T; ++t) {
        unsigned long long m = __ballot(z > 0.5f);
        if (lane == 0) wcnt[wav] = __popcll(m);
        __syncthreads();
        int cnt = 0, base = 0;
#pragma unroll
        for (int w2 = 0; w2 < 8; ++w2) {
            int c = wcnt[w2];
            if (w2 < wav) base += c;
            cnt += c;
        }
        if (z > 0.5f) {
            int pos = base + __popcll(m & ((1ull << lane) - 1ull));
            list[pos] = u;
        }
        float ii = volt_b[t * NR + u];
        __syncthreads();

        float s1 = 0.f, s2 = 0.f;
        int k = 0;
        for (; k + 8 <= cnt; k += 8) {
            int4 ja = *(const int4*)&list[k];
            int4 jb = *(const int4*)&list[k + 4];
            int j0 = __builtin_amdgcn_readfirstlane(ja.x);
            int j1 = __builtin_amdgcn_readfirstlane(ja.y);
            int j2 = __builtin_amdgcn_readfirstlane(ja.z);
            int j3 = __builtin_amdgcn_readfirstlane(ja.w);
            int j4 = __builtin_amdgcn_readfirstlane(jb.x);
            int j5 = __builtin_amdgcn_readfirstlane(jb.y);
            int j6 = __builtin_amdgcn_readfirstlane(jb.z);
            int j7 = __builtin_amdgcn_readfirstlane(jb.w);
            float w0 = w_rec[j0 * NR + u]; if (j0 == u) w0 = 0.f;
            float w1 = w_rec[j1 * NR + u]; if (j1 == u) w1 = 0.f;
            float w2 = w_rec[j2 * NR + u]; if (j2 == u) w2 = 0.f;
            float w3 = w_rec[j3 * NR + u]; if (j3 == u) w3 = 0.f;
            float w4 = w_rec[j4 * NR + u]; if (j4 == u) w4 = 0.f;
            float w5 = w_rec[j5 * NR + u]; if (j5 == u) w5 = 0.f;
            float w6 = w_rec[j6 * NR + u]; if (j6 == u) w6 = 0.f;
            float w7 = w_rec[j7 * NR + u]; if (j7 == u) w7 = 0.f;
            if (j0 < KC) s1 = __fadd_rn(s1, w0); else s2 = __fadd_rn(s2, w0);
            if (j1 < KC) s1 = __fadd_rn(s1, w1); else s2 = __fadd_rn(s2, w1);
            if (j2 < KC) s1 = __fadd_rn(s1, w2); else s2 = __fadd_rn(s2, w2);
            if (j3 < KC) s1 = __fadd_rn(s1, w3); else s2 = __fadd_rn(s2, w3);
            if (j4 < KC) s1 = __fadd_rn(s1, w4); else s2 = __fadd_rn(s2, w4);
            if (j5 < KC) s1 = __fadd_rn(s1, w5); else s2 = __fadd_rn(s2, w5);
            if (j6 < KC) s1 = __fadd_rn(s1, w6); else s2 = __fadd_rn(s2, w6);
            if (j7 < KC) s1 = __fadd_rn(s1, w7); else s2 = __fadd_rn(s2, w7);
        }
        for (; k < cnt; ++k) {
            int j = __builtin_amdgcn_readfirstlane(list[k]);
            float w = w_rec[j * NR + u];
            if (j == u) w = 0.f;
            if (j < KC) s1 = __fadd_rn(s1, w); else s2 = __fadd_rn(s2, w);
        }
        float rec = __fadd_rn(s1, s2);

        float it = __fadd_rn(ii, rec);
        float m1 = mul_nofma(decay, v);
        float t2 = __fadd_rn(m1, it);
        float vn = __fsub_rn(t2, z);
        float zn = (vn > 1.0f) ? 1.0f : 0.0f;
        volt_b[t * NR + u] = vn;
        spk_b[t * NR + u]  = zn;

        double p = (double)zn * wo;
#pragma unroll
        for (int o = 32; o > 0; o >>= 1) p += __shfl_xor(p, o, 64);
        if (lane == 0) projp[wav] = p;
        __syncthreads();
        if (u == 0) {
            double pr = bo;
#pragma unroll
            for (int w2 = 0; w2 < 8; ++w2) pr += projp[w2];
            ema = 0.8 * ema + 0.2 * pr;
            pred[b * T + t] = (float)ema;
        }
        v = vn; z = zn;
    }
}

extern "C" void kernel_launch(void* const* d_in, const int* in_sizes, int n_in,
                              void* d_out, int out_size, void* d_ws, size_t ws_size,
                              hipStream_t stream) {
    const float* inputs = (const float*)d_in[0];
    const float* w_in   = (const float*)d_in[1];
    const float* w_rec  = (const float*)d_in[2];
    const float* w_out  = (const float*)d_in[3];
    const float* b_out  = (const float*)d_in[4];
    float* out = (float*)d_out;

    k_in_gemm<16><<<dim3(B * T / 16), dim3(512), 0, stream>>>(inputs, w_in, out);

    const size_t need = (size_t)(NR + 1) * NR * sizeof(float);
    if (ws_size >= need) {
        float* w_ws = (float*)d_ws;
        k_prep<<<dim3(NR + 1), dim3(512), 0, stream>>>(w_rec, w_ws);
        k_scan<<<dim3(B), dim3(512), 0, stream>>>(w_ws, out);
        k_pred<<<dim3(B), dim3(512), 0, stream>>>(w_out, b_out, out);
    } else {
        k_scan_ref<<<dim3(B), dim3(512), 0, stream>>>(w_rec, w_out, b_out, out);
    }
}

// Round 19
// 2416.616 us; speedup vs baseline: 1.4345x; 1.4345x over previous
//
#include <hip/hip_runtime.h>

#define NR 512
#define NI 128
#define B 32
#define T 1000
#define G 32          // load-group width; 2 buffers x 32 floats = 64 VGPRs of data
#define LA (256 + G)  // per-panel list capacity incl. permanent zero-row pad
// Locked numeric model (verified PASS rounds 13-18):
//  - input GEMM: per element single ascending-i FMA chain.
//  - z @ w_rec_masked: two 256-wide ascending-k chains (OpenBLAS K-panel
//    rebalancing: [0,256)+[256,512)), joined by one rounded add.
//    Binary z => only active rows; masked diag and zero-row pads are exact +0.
//    s1/s2 independent -> panel-separated walk is bit-identical.
//  - elementwise: separate rounded f32 ops ((f32(decay)*v) + i_t) - z.
//  - pred: EMA over (b_out + spikes@w_out), f64, post-hoc in k_pred (loose tol).
// This round: R16's proven compiler-managed depth-2 pipeline (VGPR=40, no
// spill) + LDS-only barriers (no vmcnt(0) store/prefetch drain) + proj/EMA
// out of the loop + G 16->32 (halves serialized L2 round-trips).

__device__ __forceinline__ float mul_nofma(float a, float b) {
    float r = a * b;
    asm volatile("" : "+v"(r));
    return r;
}

// LDS-only barrier: waits LDS ops, leaves global loads/stores in flight.
__device__ __forceinline__ void bar_lds() {
    asm volatile("s_waitcnt lgkmcnt(0)\n\ts_barrier" ::: "memory");
}

// ---------------- Kernel 0: masked w_rec copy + zero row into d_ws
__global__ __launch_bounds__(512) void k_prep(const float* __restrict__ w_rec,
                                              float* __restrict__ w_ws) {
    const int r = blockIdx.x, u = threadIdx.x;
    float val = 0.f;
    if (r < NR && r != u) val = w_rec[r * NR + u];
    w_ws[r * NR + u] = val;
}

// ---------------- Kernel 1: i_in = inputs @ w_in -> voltages region of d_out
template <int ROWS>
__global__ __launch_bounds__(512) void k_in_gemm(const float* __restrict__ inputs,
                                                 const float* __restrict__ w_in,
                                                 float* __restrict__ i_in) {
    const int u = threadIdx.x;
    const int r0 = blockIdx.x * ROWS;
    float acc[ROWS];
#pragma unroll
    for (int r = 0; r < ROWS; ++r) acc[r] = 0.f;
    const float* __restrict__ inp = inputs + (long)r0 * NI;
#pragma unroll 4
    for (int i = 0; i < NI; ++i) {
        float w = w_in[i * NR + u];
#pragma unroll
        for (int r = 0; r < ROWS; ++r)
            acc[r] = __builtin_fmaf(inp[r * NI + i], w, acc[r]);   // ascending i, FMA
    }
#pragma unroll
    for (int r = 0; r < ROWS; ++r)
        i_in[(long)(r0 + r) * NR + u] = acc[r];
}

// ---- pipelined helpers: compiler-managed loads, static buffer indexing
__device__ __forceinline__ void loadg(float (&buf)[G], int g, int nlo,
                                      const int* __restrict__ listA,
                                      const int* __restrict__ listB,
                                      const float* __restrict__ w_ws, int u) {
    const int* lp = (g < nlo) ? (listA + g * G) : (listB + (g - nlo) * G);
#pragma unroll
    for (int qq = 0; qq < G / 4; ++qq) {
        int4 jv = *(const int4*)(lp + qq * 4);
        int j0 = __builtin_amdgcn_readfirstlane(jv.x);
        int j1 = __builtin_amdgcn_readfirstlane(jv.y);
        int j2 = __builtin_amdgcn_readfirstlane(jv.z);
        int j3 = __builtin_amdgcn_readfirstlane(jv.w);
        buf[qq * 4 + 0] = w_ws[j0 * NR + u];
        buf[qq * 4 + 1] = w_ws[j1 * NR + u];
        buf[qq * 4 + 2] = w_ws[j2 * NR + u];
        buf[qq * 4 + 3] = w_ws[j3 * NR + u];
    }
}

__device__ __forceinline__ void sumg(const float (&buf)[G], int g, int nlo,
                                     float& s1, float& s2) {
    float& s = (g < nlo) ? s1 : s2;
#pragma unroll
    for (int q = 0; q < G; ++q) s = __fadd_rn(s, buf[q]);
}

// ---------------- Kernel 2: per-batch LIF scan, depth-2 pipelined G=32 groups.
// 32 blocks x 512 threads; 2 LDS-only barriers/step; no proj/EMA in-loop.
__global__ __launch_bounds__(512) void k_scan(const float* __restrict__ w_ws,
                                              float* __restrict__ out) {
    const int b = blockIdx.x;
    const int u = threadIdx.x;
    const int wav = u >> 6, lane = u & 63;

    float* __restrict__ volt_b = out + (long)b * (T * NR);                 // also i_in (in-place)
    float* __restrict__ spk_b  = out + (long)B * T * NR + (long)b * (T * NR);

    __shared__ __align__(16) int listA[LA];
    __shared__ __align__(16) int listB[LA];
    __shared__ int wcnt[8];

    // permanent zero-row pads (tail-group overshoot within each panel list)
    if (u >= 256 && u < 256 + G) { listA[u] = NR; listB[u] = NR; }

    float v = 0.f, z = 0.f;
    const float decay = 0.951229424500714f;   // f32 rounding of the python scalar
    __syncthreads();

    for (int t = 0; t < T; ++t) {
        float ii = volt_b[t * NR + u];         // prefetch; not drained by bar_lds

        unsigned long long m = __ballot(z > 0.5f);
        if (lane == 0) wcnt[wav] = __popcll(m);
        bar_lds();                             // A: wcnt ready

        const int c0 = wcnt[0], c1 = wcnt[1], c2 = wcnt[2], c3 = wcnt[3];
        const int c4 = wcnt[4], c5 = wcnt[5], c6 = wcnt[6], c7 = wcnt[7];
        const int cnt_lo = c0 + c1 + c2 + c3;
        const int cnt_hi = c4 + c5 + c6 + c7;

        // scatter actives into per-panel lists (ascending u within each panel)
        if (z > 0.5f) {
            int below = __popcll(m & ((1ull << lane) - 1ull));
            if (wav < 4) {
                int pos = (wav > 0 ? c0 : 0) + (wav > 1 ? c1 : 0) + (wav > 2 ? c2 : 0) + below;
                listA[pos] = u;
            } else {
                int pos = (wav > 4 ? c4 : 0) + (wav > 5 ? c5 : 0) + (wav > 6 ? c6 : 0) + below;
                listB[pos] = u;
            }
        }
        // refresh stale slots -> zero row (disjoint from scatter targets)
        if (u < 256) { if (u >= cnt_lo) listA[u] = NR; }
        else         { int x = u - 256; if (x >= cnt_hi) listB[x] = NR; }
        bar_lds();                             // B: lists ready

        // ---- two-panel chain, depth-2 pipelined 32-wide groups (bit-exact order)
        const int nlo = (cnt_lo + G - 1) / G;
        const int ng  = nlo + (cnt_hi + G - 1) / G;
        float s1 = 0.f, s2 = 0.f;
        if (ng > 0) {
            float bA[G], bB[G];
            loadg(bA, 0, nlo, listA, listB, w_ws, u);
            int g = 0;
            while (true) {
                if (g + 1 < ng) loadg(bB, g + 1, nlo, listA, listB, w_ws, u);
                sumg(bA, g, nlo, s1, s2);
                ++g;
                if (g == ng) break;
                if (g + 1 < ng) loadg(bA, g + 1, nlo, listA, listB, w_ws, u);
                sumg(bB, g, nlo, s1, s2);
                ++g;
                if (g == ng) break;
            }
        }
        float rec = __fadd_rn(s1, s2);         // panel join (one rounded add)

        // ---- LIF update (reference op order, no contraction)
        float it = __fadd_rn(ii, rec);
        float m1 = mul_nofma(decay, v);
        float t2 = __fadd_rn(m1, it);
        float vn = __fsub_rn(t2, z);
        float zn = (vn > 1.0f) ? 1.0f : 0.0f;
        volt_b[t * NR + u] = vn;
        spk_b[t * NR + u]  = zn;
        v = vn; z = zn;
    }
}

// ---------------- Kernel 3: pred = EMA(b_out + spikes @ w_out), post-hoc.
__global__ __launch_bounds__(512) void k_pred(const float* __restrict__ w_out,
                                              const float* __restrict__ b_out,
                                              float* __restrict__ out) {
    const int b = blockIdx.x;
    const int tid = threadIdx.x;
    const int wav = tid >> 6, lane = tid & 63;
    const float* __restrict__ spk_b = out + (long)B * T * NR + (long)b * (T * NR);
    float* __restrict__ pred = out + 2L * B * T * NR + (long)b * T;

    __shared__ double projs[T];   // 8 KB

    double wo[8];
#pragma unroll
    for (int q = 0; q < 8; ++q) wo[q] = (double)w_out[lane + q * 64];

    for (int t = wav; t < T; t += 8) {
        double p = 0.0;
#pragma unroll
        for (int q = 0; q < 8; ++q)
            p += (double)spk_b[t * NR + lane + q * 64] * wo[q];
#pragma unroll
        for (int o = 32; o > 0; o >>= 1) p += __shfl_xor(p, o, 64);
        if (lane == 0) projs[t] = p;
    }
    __syncthreads();
    if (tid == 0) {
        const double bo = (double)b_out[0];
        double ema = 0.0;
        for (int t = 0; t < T; ++t) {
            ema = 0.8 * ema + 0.2 * (bo + projs[t]);
            pred[t] = (float)ema;
        }
    }
}

// ---------------- Fallback: verified round-13 scan (no d_ws needed)
__global__ __launch_bounds__(512) void k_scan_ref(const float* __restrict__ w_rec,
                                                  const float* __restrict__ w_out,
                                                  const float* __restrict__ b_out,
                                                  float* __restrict__ out) {
    const int b = blockIdx.x;
    const int u = threadIdx.x;
    const int wav = u >> 6, lane = u & 63;
    const int KC = 256;

    float* __restrict__ volt_b = out + (long)b * (T * NR);
    float* __restrict__ spk_b  = out + (long)B * T * NR + (long)b * (T * NR);
    float* __restrict__ pred   = out + 2L * B * T * NR;

    __shared__ __align__(16) int list[NR];
    __shared__ int wcnt[8];
    __shared__ double projp[8];

    float v = 0.f, z = 0.f;
    const float decay = 0.951229424500714f;
    const double wo = (double)w_out[u];
    const double bo = (double)b_out[0];
    double ema = 0.0;

    for (int t = 0; t < T; ++t) {
        unsigned long long m = __ballot(z > 0.5f);
        if (lane == 0) wcnt[wav] = __popcll(m);
        __syncthreads();
        int cnt = 0, base = 0;
#pragma unroll
        for (int w2 = 0; w2 < 8; ++w2) {
            int c = wcnt[w2];
            if (w2 < wav) base += c;
            cnt += c;
        }
        if (z > 0.5f) {
            int pos = base + __popcll(m & ((1ull << lane) - 1ull));
            list[pos] = u;
        }
        float ii = volt_b[t * NR + u];
        __syncthreads();

        float s1 = 0.f, s2 = 0.f;
        int k = 0;
        for (; k + 8 <= cnt; k += 8) {
            int4 ja = *(const int4*)&list[k];
            int4 jb = *(const int4*)&list[k + 4];
            int j0 = __builtin_amdgcn_readfirstlane(ja.x);
            int j1 = __builtin_amdgcn_readfirstlane(ja.y);
            int j2 = __builtin_amdgcn_readfirstlane(ja.z);
            int j3 = __builtin_amdgcn_readfirstlane(ja.w);
            int j4 = __builtin_amdgcn_readfirstlane(jb.x);
            int j5 = __builtin_amdgcn_readfirstlane(jb.y);
            int j6 = __builtin_amdgcn_readfirstlane(jb.z);
            int j7 = __builtin_amdgcn_readfirstlane(jb.w);
            float w0 = w_rec[j0 * NR + u]; if (j0 == u) w0 = 0.f;
            float w1 = w_rec[j1 * NR + u]; if (j1 == u) w1 = 0.f;
            float w2 = w_rec[j2 * NR + u]; if (j2 == u) w2 = 0.f;
            float w3 = w_rec[j3 * NR + u]; if (j3 == u) w3 = 0.f;
            float w4 = w_rec[j4 * NR + u]; if (j4 == u) w4 = 0.f;
            float w5 = w_rec[j5 * NR + u]; if (j5 == u) w5 = 0.f;
            float w6 = w_rec[j6 * NR + u]; if (j6 == u) w6 = 0.f;
            float w7 = w_rec[j7 * NR + u]; if (j7 == u) w7 = 0.f;
            if (j0 < KC) s1 = __fadd_rn(s1, w0); else s2 = __fadd_rn(s2, w0);
            if (j1 < KC) s1 = __fadd_rn(s1, w1); else s2 = __fadd_rn(s2, w1);
            if (j2 < KC) s1 = __fadd_rn(s1, w2); else s2 = __fadd_rn(s2, w2);
            if (j3 < KC) s1 = __fadd_rn(s1, w3); else s2 = __fadd_rn(s2, w3);
            if (j4 < KC) s1 = __fadd_rn(s1, w4); else s2 = __fadd_rn(s2, w4);
            if (j5 < KC) s1 = __fadd_rn(s1, w5); else s2 = __fadd_rn(s2, w5);
            if (j6 < KC) s1 = __fadd_rn(s1, w6); else s2 = __fadd_rn(s2, w6);
            if (j7 < KC) s1 = __fadd_rn(s1, w7); else s2 = __fadd_rn(s2, w7);
        }
        for (; k < cnt; ++k) {
            int j = __builtin_amdgcn_readfirstlane(list[k]);
            float w = w_rec[j * NR + u];
            if (j == u) w = 0.f;
            if (j < KC) s1 = __fadd_rn(s1, w); else s2 = __fadd_rn(s2, w);
        }
        float rec = __fadd_rn(s1, s2);

        float it = __fadd_rn(ii, rec);
        float m1 = mul_nofma(decay, v);
        float t2 = __fadd_rn(m1, it);
        float vn = __fsub_rn(t2, z);
        float zn = (vn > 1.0f) ? 1.0f : 0.0f;
        volt_b[t * NR + u] = vn;
        spk_b[t * NR + u]  = zn;

        double p = (double)zn * wo;
#pragma unroll
        for (int o = 32; o > 0; o >>= 1) p += __shfl_xor(p, o, 64);
        if (lane == 0) projp[wav] = p;
        __syncthreads();
        if (u == 0) {
            double pr = bo;
#pragma unroll
            for (int w2 = 0; w2 < 8; ++w2) pr += projp[w2];
            ema = 0.8 * ema + 0.2 * pr;
            pred[b * T + t] = (float)ema;
        }
        v = vn; z = zn;
    }
}

extern "C" void kernel_launch(void* const* d_in, const int* in_sizes, int n_in,
                              void* d_out, int out_size, void* d_ws, size_t ws_size,
                              hipStream_t stream) {
    const float* inputs = (const float*)d_in[0];
    const float* w_in   = (const float*)d_in[1];
    const float* w_rec  = (const float*)d_in[2];
    const float* w_out  = (const float*)d_in[3];
    const float* b_out  = (const float*)d_in[4];
    float* out = (float*)d_out;

    k_in_gemm<16><<<dim3(B * T / 16), dim3(512), 0, stream>>>(inputs, w_in, out);

    const size_t need = (size_t)(NR + 1) * NR * sizeof(float);
    if (ws_size >= need) {
        float* w_ws = (float*)d_ws;
        k_prep<<<dim3(NR + 1), dim3(512), 0, stream>>>(w_rec, w_ws);
        k_scan<<<dim3(B), dim3(512), 0, stream>>>(w_ws, out);
        k_pred<<<dim3(B), dim3(512), 0, stream>>>(w_out, b_out, out);
    } else {
        k_scan_ref<<<dim3(B), dim3(512), 0, stream>>>(w_rec, w_out, b_out, out);
    }
}

// Round 20
// 2184.473 us; speedup vs baseline: 1.5869x; 1.1063x over previous
//
#include <hip/hip_runtime.h>

#define NR 512
#define NI 128
#define B 32
#define T 1000
#define G 32          // load-group width; 2 buffers x 32 floats per thread
// Locked numeric model (verified PASS rounds 13-19):
//  - input GEMM: per element single ascending-i FMA chain.
//  - z @ w_rec_masked: two 256-wide ascending-k chains (OpenBLAS K-panel
//    rebalancing: [0,256)+[256,512)), joined by one rounded add.
//    Binary z => only active rows; masked diag and zero-row pads are exact +0
//    (running sums never produce -0, so fadd(s,+0)=s exactly).
//  - elementwise: separate rounded f32 ops ((f32(decay)*v) + i_t) - z.
//  - pred: EMA over (b_out + spikes@w_out), f64, post-hoc in k_pred (loose tol).
// This round: panel-parallel scan — 1024 threads, thread (u,h) sums only panel
// h (half chain) -> 4 waves/SIMD TLP hides L2 latency; partials joined via LDS
// with the locked single join-add.

__device__ __forceinline__ float mul_nofma(float a, float b) {
    float r = a * b;
    asm volatile("" : "+v"(r));
    return r;
}

// LDS-only barrier: waits LDS ops, leaves global loads/stores in flight.
__device__ __forceinline__ void bar_lds() {
    asm volatile("s_waitcnt lgkmcnt(0)\n\ts_barrier" ::: "memory");
}

// ---------------- Kernel 0: masked w_rec copy + zero row into d_ws
__global__ __launch_bounds__(512) void k_prep(const float* __restrict__ w_rec,
                                              float* __restrict__ w_ws) {
    const int r = blockIdx.x, u = threadIdx.x;
    float val = 0.f;
    if (r < NR && r != u) val = w_rec[r * NR + u];
    w_ws[r * NR + u] = val;
}

// ---------------- Kernel 1: i_in = inputs @ w_in -> voltages region of d_out
template <int ROWS>
__global__ __launch_bounds__(512) void k_in_gemm(const float* __restrict__ inputs,
                                                 const float* __restrict__ w_in,
                                                 float* __restrict__ i_in) {
    const int u = threadIdx.x;
    const int r0 = blockIdx.x * ROWS;
    float acc[ROWS];
#pragma unroll
    for (int r = 0; r < ROWS; ++r) acc[r] = 0.f;
    const float* __restrict__ inp = inputs + (long)r0 * NI;
#pragma unroll 4
    for (int i = 0; i < NI; ++i) {
        float w = w_in[i * NR + u];
#pragma unroll
        for (int r = 0; r < ROWS; ++r)
            acc[r] = __builtin_fmaf(inp[r * NI + i], w, acc[r]);   // ascending i, FMA
    }
#pragma unroll
    for (int r = 0; r < ROWS; ++r)
        i_in[(long)(r0 + r) * NR + u] = acc[r];
}

// ---- pipelined helpers: one list, static buffer indexing
__device__ __forceinline__ void loadg1(float (&buf)[G], const int* __restrict__ lp,
                                       const float* __restrict__ w_ws, int u) {
#pragma unroll
    for (int qq = 0; qq < G / 4; ++qq) {
        int4 jv = *(const int4*)(lp + qq * 4);
        int j0 = __builtin_amdgcn_readfirstlane(jv.x);
        int j1 = __builtin_amdgcn_readfirstlane(jv.y);
        int j2 = __builtin_amdgcn_readfirstlane(jv.z);
        int j3 = __builtin_amdgcn_readfirstlane(jv.w);
        buf[qq * 4 + 0] = w_ws[j0 * NR + u];
        buf[qq * 4 + 1] = w_ws[j1 * NR + u];
        buf[qq * 4 + 2] = w_ws[j2 * NR + u];
        buf[qq * 4 + 3] = w_ws[j3 * NR + u];
    }
}

__device__ __forceinline__ void sumg1(const float (&buf)[G], float& s) {
#pragma unroll
    for (int q = 0; q < G; ++q) s = __fadd_rn(s, buf[q]);
}

// ---------------- Kernel 2: per-batch LIF scan, panel-parallel (u,h) threads.
// 32 blocks x 1024 threads; thread (u,h) sums panel h's chain for column u.
// 3 LDS-only barriers/step; no proj/EMA in-loop.
__global__ __launch_bounds__(1024) void k_scan(const float* __restrict__ w_ws,
                                               float* __restrict__ out) {
    const int b = blockIdx.x;
    const int tid = threadIdx.x;
    const int u = tid & (NR - 1);
    const int h = tid >> 9;            // 0: panel j<256, 1: panel j>=256
    const int wav = tid >> 6;          // 0..15; waves 0..7 are h=0
    const int lane = tid & 63;

    float* __restrict__ volt_b = out + (long)b * (T * NR);                 // also i_in (in-place)
    float* __restrict__ spk_b  = out + (long)B * T * NR + (long)b * (T * NR);

    __shared__ __align__(16) int listA[256];
    __shared__ __align__(16) int listB[256];
    __shared__ int wcnt[8];
    __shared__ float shs[2][NR];

    float v = 0.f, z = 0.f;
    const float decay = 0.951229424500714f;   // f32 rounding of the python scalar
    __syncthreads();

    for (int t = 0; t < T; ++t) {
        float ii = volt_b[t * NR + u];         // prefetch (vmcnt; survives bar_lds)

        // ---- ballot: z == spikes[t-1]; h=0 waves publish counts
        unsigned long long m = __ballot(z > 0.5f);
        if (h == 0 && lane == 0) wcnt[wav] = __popcll(m);
        bar_lds();                             // A: wcnt ready

        const int c0 = wcnt[0], c1 = wcnt[1], c2 = wcnt[2], c3 = wcnt[3];
        const int c4 = wcnt[4], c5 = wcnt[5], c6 = wcnt[6], c7 = wcnt[7];
        const int cnt_lo = c0 + c1 + c2 + c3;
        const int cnt_hi = c4 + c5 + c6 + c7;

        // ---- h=0 threads build both per-panel lists (ascending u per panel)
        if (h == 0) {
            if (z > 0.5f) {
                int below = __popcll(m & ((1ull << lane) - 1ull));
                if (wav < 4) {
                    int pos = (wav > 0 ? c0 : 0) + (wav > 1 ? c1 : 0) + (wav > 2 ? c2 : 0) + below;
                    listA[pos] = u;
                } else {
                    int pos = (wav > 4 ? c4 : 0) + (wav > 5 ? c5 : 0) + (wav > 6 ? c6 : 0) + below;
                    listB[pos] = u;
                }
            }
            // refresh stale slots -> zero row (disjoint from scatter targets)
            if (u < 256) { if (u >= cnt_lo) listA[u] = NR; }
            else         { int x = u - 256; if (x >= cnt_hi) listB[x] = NR; }
        }
        bar_lds();                             // B: lists ready

        // ---- own-panel chain, depth-2 pipelined 32-wide groups (bit-exact order)
        const int* lp  = h ? listB : listA;
        const int  myn = h ? ((cnt_hi + G - 1) / G) : ((cnt_lo + G - 1) / G);
        float s = 0.f;
        if (myn > 0) {
            float bA[G], bB[G];
            loadg1(bA, lp, w_ws, u);
            int g = 0;
            while (true) {
                if (g + 1 < myn) loadg1(bB, lp + (g + 1) * G, w_ws, u);
                sumg1(bA, s);
                ++g;
                if (g == myn) break;
                if (g + 1 < myn) loadg1(bA, lp + (g + 1) * G, w_ws, u);
                sumg1(bB, s);
                ++g;
                if (g == myn) break;
            }
        }
        shs[h][u] = s;
        bar_lds();                             // C: both partials ready

        // ---- join + LIF update (reference op order, no contraction)
        float rec = __fadd_rn(shs[0][u], shs[1][u]);
        float it = __fadd_rn(ii, rec);
        float m1 = mul_nofma(decay, v);
        float t2 = __fadd_rn(m1, it);
        float vn = __fsub_rn(t2, z);
        float zn = (vn > 1.0f) ? 1.0f : 0.0f;
        if (h == 0) {
            volt_b[t * NR + u] = vn;
            spk_b[t * NR + u]  = zn;
        }
        v = vn; z = zn;                        // identical in both halves
    }
}

// ---------------- Kernel 3: pred = EMA(b_out + spikes @ w_out), post-hoc.
__global__ __launch_bounds__(512) void k_pred(const float* __restrict__ w_out,
                                              const float* __restrict__ b_out,
                                              float* __restrict__ out) {
    const int b = blockIdx.x;
    const int tid = threadIdx.x;
    const int wav = tid >> 6, lane = tid & 63;
    const float* __restrict__ spk_b = out + (long)B * T * NR + (long)b * (T * NR);
    float* __restrict__ pred = out + 2L * B * T * NR + (long)b * T;

    __shared__ double projs[T];   // 8 KB

    double wo[8];
#pragma unroll
    for (int q = 0; q < 8; ++q) wo[q] = (double)w_out[lane + q * 64];

    for (int t = wav; t < T; t += 8) {
        double p = 0.0;
#pragma unroll
        for (int q = 0; q < 8; ++q)
            p += (double)spk_b[t * NR + lane + q * 64] * wo[q];
#pragma unroll
        for (int o = 32; o > 0; o >>= 1) p += __shfl_xor(p, o, 64);
        if (lane == 0) projs[t] = p;
    }
    __syncthreads();
    if (tid == 0) {
        const double bo = (double)b_out[0];
        double ema = 0.0;
        for (int t = 0; t < T; ++t) {
            ema = 0.8 * ema + 0.2 * (bo + projs[t]);
            pred[t] = (float)ema;
        }
    }
}

// ---------------- Fallback: verified round-13 scan (no d_ws needed)
__global__ __launch_bounds__(512) void k_scan_ref(const float* __restrict__ w_rec,
                                                  const float* __restrict__ w_out,
                                                  const float* __restrict__ b_out,
                                                  float* __restrict__ out) {
    const int b = blockIdx.x;
    const int u = threadIdx.x;
    const int wav = u >> 6, lane = u & 63;
    const int KC = 256;

    float* __restrict__ volt_b = out + (long)b * (T * NR);
    float* __restrict__ spk_b  = out + (long)B * T * NR + (long)b * (T * NR);
    float* __restrict__ pred   = out + 2L * B * T * NR;

    __shared__ __align__(16) int list[NR];
    __shared__ int wcnt[8];
    __shared__ double projp[8];

    float v = 0.f, z = 0.f;
    const float decay = 0.951229424500714f;
    const double wo = (double)w_out[u];
    const double bo = (double)b_out[0];
    double ema = 0.0;

    for (int t = 0; t < T; ++t) {
        unsigned long long m = __ballot(z > 0.5f);
        if (lane == 0) wcnt[wav] = __popcll(m);
        __syncthreads();
        int cnt = 0, base = 0;
#pragma unroll
        for (int w2 = 0; w2 < 8; ++w2) {
            int c = wcnt[w2];
            if (w2 < wav) base += c;
            cnt += c;
        }
        if (z > 0.5f) {
            int pos = base + __popcll(m & ((1ull << lane) - 1ull));
            list[pos] = u;
        }
        float ii = volt_b[t * NR + u];
        __syncthreads();

        float s1 = 0.f, s2 = 0.f;
        int k = 0;
        for (; k + 8 <= cnt; k += 8) {
            int4 ja = *(const int4*)&list[k];
            int4 jb = *(const int4*)&list[k + 4];
            int j0 = __builtin_amdgcn_readfirstlane(ja.x);
            int j1 = __builtin_amdgcn_readfirstlane(ja.y);
            int j2 = __builtin_amdgcn_readfirstlane(ja.z);
            int j3 = __builtin_amdgcn_readfirstlane(ja.w);
            int j4 = __builtin_amdgcn_readfirstlane(jb.x);
            int j5 = __builtin_amdgcn_readfirstlane(jb.y);
            int j6 = __builtin_amdgcn_readfirstlane(jb.z);
            int j7 = __builtin_amdgcn_readfirstlane(jb.w);
            float w0 = w_rec[j0 * NR + u]; if (j0 == u) w0 = 0.f;
            float w1 = w_rec[j1 * NR + u]; if (j1 == u) w1 = 0.f;
            float w2 = w_rec[j2 * NR + u]; if (j2 == u) w2 = 0.f;
            float w3 = w_rec[j3 * NR + u]; if (j3 == u) w3 = 0.f;
            float w4 = w_rec[j4 * NR + u]; if (j4 == u) w4 = 0.f;
            float w5 = w_rec[j5 * NR + u]; if (j5 == u) w5 = 0.f;
            float w6 = w_rec[j6 * NR + u]; if (j6 == u) w6 = 0.f;
            float w7 = w_rec[j7 * NR + u]; if (j7 == u) w7 = 0.f;
            if (j0 < KC) s1 = __fadd_rn(s1, w0); else s2 = __fadd_rn(s2, w0);
            if (j1 < KC) s1 = __fadd_rn(s1, w1); else s2 = __fadd_rn(s2, w1);
            if (j2 < KC) s1 = __fadd_rn(s1, w2); else s2 = __fadd_rn(s2, w2);
            if (j3 < KC) s1 = __fadd_rn(s1, w3); else s2 = __fadd_rn(s2, w3);
            if (j4 < KC) s1 = __fadd_rn(s1, w4); else s2 = __fadd_rn(s2, w4);
            if (j5 < KC) s1 = __fadd_rn(s1, w5); else s2 = __fadd_rn(s2, w5);
            if (j6 < KC) s1 = __fadd_rn(s1, w6); else s2 = __fadd_rn(s2, w6);
            if (j7 < KC) s1 = __fadd_rn(s1, w7); else s2 = __fadd_rn(s2, w7);
        }
        for (; k < cnt; ++k) {
            int j = __builtin_amdgcn_readfirstlane(list[k]);
            float w = w_rec[j * NR + u];
            if (j == u) w = 0.f;
            if (j < KC) s1 = __fadd_rn(s1, w); else s2 = __fadd_rn(s2, w);
        }
        float rec = __fadd_rn(s1, s2);

        float it = __fadd_rn(ii, rec);
        float m1 = mul_nofma(decay, v);
        float t2 = __fadd_rn(m1, it);
        float vn = __fsub_rn(t2, z);
        float zn = (vn > 1.0f) ? 1.0f : 0.0f;
        volt_b[t * NR + u] = vn;
        spk_b[t * NR + u]  = zn;

        double p = (double)zn * wo;
#pragma unroll
        for (int o = 32; o > 0; o >>= 1) p += __shfl_xor(p, o, 64);
        if (lane == 0) projp[wav] = p;
        __syncthreads();
        if (u == 0) {
            double pr = bo;
#pragma unroll
            for (int w2 = 0; w2 < 8; ++w2) pr += projp[w2];
            ema = 0.8 * ema + 0.2 * pr;
            pred[b * T + t] = (float)ema;
        }
        v = vn; z = zn;
    }
}

extern "C" void kernel_launch(void* const* d_in, const int* in_sizes, int n_in,
                              void* d_out, int out_size, void* d_ws, size_t ws_size,
                              hipStream_t stream) {
    const float* inputs = (const float*)d_in[0];
    const float* w_in   = (const float*)d_in[1];
    const float* w_rec  = (const float*)d_in[2];
    const float* w_out  = (const float*)d_in[3];
    const float* b_out  = (const float*)d_in[4];
    float* out = (float*)d_out;

    k_in_gemm<16><<<dim3(B * T / 16), dim3(512), 0, stream>>>(inputs, w_in, out);

    const size_t need = (size_t)(NR + 1) * NR * sizeof(float);
    if (ws_size >= need) {
        float* w_ws = (float*)d_ws;
        k_prep<<<dim3(NR + 1), dim3(512), 0, stream>>>(w_rec, w_ws);
        k_scan<<<dim3(B), dim3(1024), 0, stream>>>(w_ws, out);
        k_pred<<<dim3(B), dim3(512), 0, stream>>>(w_out, b_out, out);
    } else {
        k_scan_ref<<<dim3(B), dim3(512), 0, stream>>>(w_rec, w_out, b_out, out);
    }
}